// Round 5
// baseline (372.991 us; speedup 1.0000x reference)
//
#include <hip/hip_runtime.h>
#include <hip/hip_bf16.h>

typedef __attribute__((ext_vector_type(8))) short short8;
typedef __attribute__((ext_vector_type(4))) float floatx4;
typedef __attribute__((ext_vector_type(8))) _Float16 half8;
typedef __attribute__((ext_vector_type(4))) _Float16 half4;

using bf16 = __hip_bfloat16;
using fp16 = _Float16;

#define S_LEN 2048
#define DM 1024
#define NH 16
#define DH 64
#define WIN 256

// ---------- helpers ----------
__device__ __forceinline__ unsigned short f2b(float f) {
  __hip_bfloat16 h = __float2bfloat16(f);
  return *reinterpret_cast<unsigned short*>(&h);
}
__device__ __forceinline__ unsigned short f2h(float f) {
  fp16 h = (fp16)f;
  return *reinterpret_cast<unsigned short*>(&h);
}
__device__ __forceinline__ void lds_load16(void* lds, const void* gptr) {
  __builtin_amdgcn_global_load_lds(
      (const __attribute__((address_space(1))) unsigned int*)gptr,
      (__attribute__((address_space(3))) unsigned int*)lds, 16, 0, 0);
}

// ---------- K1: x fp32 -> bf16 ----------
__global__ __launch_bounds__(256) void k_convert_x(const float4* __restrict__ in,
                                                   ushort4* __restrict__ out) {
  int i = blockIdx.x * 256 + threadIdx.x;
  float4 v = in[i];
  ushort4 r;
  r.x = f2b(v.x); r.y = f2b(v.y); r.z = f2b(v.z); r.w = f2b(v.w);
  out[i] = r;
}

// ---------- K2: W[k][n] fp32 -> Wt[n][k] bf16 (4 matrices) ----------
__global__ __launch_bounds__(256) void k_transpose_cvt(const float* __restrict__ W0,
                                                       const float* __restrict__ W1,
                                                       const float* __restrict__ W2,
                                                       const float* __restrict__ W3,
                                                       bf16* __restrict__ out) {
  __shared__ float t[32][33];
  const float* W = (blockIdx.z == 0) ? W0 : (blockIdx.z == 1) ? W1 : (blockIdx.z == 2) ? W2 : W3;
  bf16* O = out + (size_t)blockIdx.z * 1024 * 1024;
  int x0 = blockIdx.x * 32, y0 = blockIdx.y * 32;
  int tx = threadIdx.x, ty = threadIdx.y;  // block (32,8)
  #pragma unroll
  for (int i = 0; i < 32; i += 8) t[ty + i][tx] = W[(size_t)(y0 + ty + i) * 1024 + x0 + tx];
  __syncthreads();
  #pragma unroll
  for (int i = 0; i < 32; i += 8)
    O[(size_t)(x0 + ty + i) * 1024 + y0 + tx] = __float2bfloat16(t[tx][ty + i]);
}

// ---------- K3/K5: bf16 MFMA GEMM, C = A[M][1024] * Bt[N][1024]^T ----------
// MODE 0: N=3072 (Wq|Wk|Wv) -> Qh/Kh [bh][s][64] fp16; V transposed: Vt [bh][d][s] fp16
// MODE 1: N=1024 (Wo) -> fp32 [m][1024]
template <int MODE>
__global__ __launch_bounds__(256) void k_gemm(const bf16* __restrict__ A,
                                              const bf16* __restrict__ Bt,
                                              const float* __restrict__ bias_q,
                                              const float* __restrict__ bias_k,
                                              const float* __restrict__ bias_v,
                                              fp16* __restrict__ Qh, fp16* __restrict__ Kh,
                                              fp16* __restrict__ Vt, float* __restrict__ outF) {
  __shared__ __align__(16) bf16 As[128 * 32];
  __shared__ __align__(16) bf16 Bs[128 * 32];
  const int tid = threadIdx.x;
  const int wave = tid >> 6, lane = tid & 63;
  const int m0 = blockIdx.y * 128, n0 = blockIdx.x * 128;
  const int r0 = tid >> 2;
  const int cb = (tid & 3) * 16;
  const char* Ag = (const char*)A + (size_t)(m0 + r0) * 2048 + cb;
  const char* Bg = (const char*)Bt + (size_t)(n0 + r0) * 2048 + cb;
  char* AsW0 = (char*)As + wave * 1024;
  char* AsW1 = (char*)As + 4096 + wave * 1024;
  char* BsW0 = (char*)Bs + wave * 1024;
  char* BsW1 = (char*)Bs + 4096 + wave * 1024;
  const int wm = (wave & 1) * 64, wn = (wave >> 1) * 64;
  const int ln = lane & 15, quad = lane >> 4;

  floatx4 acc[4][4];
  #pragma unroll
  for (int i = 0; i < 4; i++)
    #pragma unroll
    for (int j = 0; j < 4; j++) acc[i][j] = (floatx4){0.f, 0.f, 0.f, 0.f};

  for (int k0 = 0; k0 < 1024; k0 += 32) {
    __syncthreads();
    lds_load16(AsW0, Ag + k0 * 2);
    lds_load16(AsW1, Ag + 64 * 2048 + k0 * 2);
    lds_load16(BsW0, Bg + k0 * 2);
    lds_load16(BsW1, Bg + 64 * 2048 + k0 * 2);
    __syncthreads();
    short8 af[4], bfr[4];
    #pragma unroll
    for (int mi = 0; mi < 4; mi++)
      af[mi] = *(const short8*)&As[(wm + mi * 16 + ln) * 32 + quad * 8];
    #pragma unroll
    for (int ni = 0; ni < 4; ni++)
      bfr[ni] = *(const short8*)&Bs[(wn + ni * 16 + ln) * 32 + quad * 8];
    #pragma unroll
    for (int mi = 0; mi < 4; mi++)
      #pragma unroll
      for (int ni = 0; ni < 4; ni++)
        acc[mi][ni] = __builtin_amdgcn_mfma_f32_16x16x32_bf16(af[mi], bfr[ni], acc[mi][ni], 0, 0, 0);
  }

  if constexpr (MODE == 0) {
    #pragma unroll
    for (int ni = 0; ni < 4; ni++) {
      int n = n0 + wn + ni * 16 + ln;  // 0..3071; g uniform across the wave
      int g = n >> 10, nn = n & 1023;
      int h = nn >> 6, dd = nn & 63;
      if (g == 2) {  // V -> Vt[bh][d][s] fp16, 4 consecutive s per 8B store
        float bias = bias_v[nn];
        #pragma unroll
        for (int mi = 0; mi < 4; mi++) {
          int m = m0 + wm + mi * 16 + quad * 4;
          int b = m >> 11, s = m & 2047;
          ushort4 pk;
          pk.x = f2h(acc[mi][ni][0] + bias);
          pk.y = f2h(acc[mi][ni][1] + bias);
          pk.z = f2h(acc[mi][ni][2] + bias);
          pk.w = f2h(acc[mi][ni][3] + bias);
          *(ushort4*)&Vt[((size_t)(b * NH + h) * DH + dd) * S_LEN + s] = pk;
        }
      } else {
        const float* bp = (g == 0) ? bias_q : bias_k;
        fp16* og = (g == 0) ? Qh : Kh;
        float bias = bp[nn];
        #pragma unroll
        for (int mi = 0; mi < 4; mi++) {
          #pragma unroll
          for (int r = 0; r < 4; r++) {
            int m = m0 + wm + mi * 16 + quad * 4 + r;
            int b = m >> 11, s = m & 2047;
            og[(size_t)((b * NH + h) * S_LEN + s) * DH + dd] = (fp16)(acc[mi][ni][r] + bias);
          }
        }
      }
    }
  } else {
    #pragma unroll
    for (int ni = 0; ni < 4; ni++) {
      int n = n0 + wn + ni * 16 + ln;
      float bias = bias_q[n];
      #pragma unroll
      for (int mi = 0; mi < 4; mi++)
        #pragma unroll
        for (int r = 0; r < 4; r++) {
          int m = m0 + wm + mi * 16 + quad * 4 + r;
          outF[(size_t)m * 1024 + n] = acc[mi][ni][r] + bias;
        }
    }
  }
}

// ---------- K4: pipelined register-resident MFMA flash attention ----------
// grid (1 + S/16, B*H), 64 threads (1 wave). blockIdx.x==0: full-softmax row
// q=0 (global query). Else: 16-query window tile, S^T trick (P stays in regs),
// K frags double-buffered one chunk ahead, global key j=0 folded into init.
__global__ __launch_bounds__(64, 3) void k_attn(const fp16* __restrict__ Qh,
                                                const fp16* __restrict__ Kh,
                                                const fp16* __restrict__ Vt,
                                                bf16* __restrict__ aout) {
  __shared__ float sLds[2048];
  const int lane = threadIdx.x;
  const int bh = blockIdx.y;
  const int b = bh >> 4, h = bh & 15;
  const size_t base = (size_t)bh * S_LEN * DH;
  const fp16* Qp = Qh + base;
  const fp16* Kp = Kh + base;
  const fp16* Vp = Vt + base;  // [d][s]

  const float SC2 = 0.18033688011112042f;  // 0.125 * log2(e)

  if (blockIdx.x == 0) {
    // ===== global query row q=0: softmax over ALL 2048 keys =====
    const int g = lane >> 3, t = lane & 7;
    const half8 q0t = *(const half8*)(Qp + t * 8);  // q0[d], d = t*8..t*8+7
    float mloc = -3.0e38f;
    for (int i = 0; i < 256; ++i) {
      // flat half8 f = i*64 + lane  ->  key j = i*8+g, d-slice t
      const half8 kv = *(const half8*)(Kp + (size_t)(i * 64 + lane) * 8);
      float p = 0.f;
      #pragma unroll
      for (int e = 0; e < 8; ++e) p += (float)q0t[e] * (float)kv[e];
      p += __shfl_xor(p, 1, 64);
      p += __shfl_xor(p, 2, 64);
      p += __shfl_xor(p, 4, 64);
      p *= SC2;
      if (t == 0) sLds[i * 8 + g] = p;
      mloc = fmaxf(mloc, p);
    }
    #pragma unroll
    for (int off = 1; off < 64; off <<= 1) mloc = fmaxf(mloc, __shfl_xor(mloc, off, 64));
    __syncthreads();
    float lsum = 0.f;
    #pragma unroll
    for (int i = 0; i < 32; ++i) {
      int j = i * 64 + lane;
      float p = exp2f(sLds[j] - mloc);
      sLds[j] = p;
      lsum += p;
    }
    #pragma unroll
    for (int off = 1; off < 64; off <<= 1) lsum += __shfl_xor(lsum, off, 64);
    __syncthreads();
    float o = 0.f;  // d = lane
    for (int j0 = 0; j0 < 2048; j0 += 8) {
      half8 vv = *(const half8*)(Vp + (size_t)lane * S_LEN + j0);
      #pragma unroll
      for (int e = 0; e < 8; ++e) o += sLds[j0 + e] * (float)vv[e];
    }
    aout[(size_t)(b * S_LEN) * DM + h * DH + lane] = __float2bfloat16(o / lsum);
    return;
  }

  // ===== window tile: 16 queries per wave =====
  const int ln = lane & 15, quad = lane >> 4;
  const int qw = (blockIdx.x - 1) * 16;

  const half8 bq0 = *(const half8*)(Qp + (size_t)(qw + ln) * DH + quad * 8);
  const half8 bq1 = *(const half8*)(Qp + (size_t)(qw + ln) * DH + 32 + quad * 8);

  floatx4 acc[4];  // O^T tiles: d = dt*16+quad*4+r, col q = ln
  float m_i, l_i;

  // ---- init: fold global key j=0 as a rank-1 contribution (p0 = 1) ----
  {
    const half8 k0a = *(const half8*)(Kp + quad * 8);
    const half8 k0b = *(const half8*)(Kp + 32 + quad * 8);
    float s0 = 0.f;
    #pragma unroll
    for (int e = 0; e < 8; ++e)
      s0 += (float)bq0[e] * (float)k0a[e] + (float)bq1[e] * (float)k0b[e];
    s0 += __shfl_xor(s0, 16, 64);
    s0 += __shfl_xor(s0, 32, 64);
    m_i = s0 * SC2;
    l_i = 1.f;
    #pragma unroll
    for (int dt = 0; dt < 4; ++dt)
      #pragma unroll
      for (int r = 0; r < 4; ++r)
        acc[dt][r] = (float)Vp[(size_t)(dt * 16 + quad * 4 + r) * S_LEN];
  }

  auto loadK = [&](int c, half8* k) {
    #pragma unroll
    for (int jt = 0; jt < 4; ++jt) {
      const fp16* kr = Kp + (size_t)(c + jt * 16 + ln) * DH;
      k[2 * jt]     = *(const half8*)(kr + quad * 8);
      k[2 * jt + 1] = *(const half8*)(kr + 32 + quad * 8);
    }
  };

  auto body = [&](int c, const half8* k) {
    // ---- S^T = K Q^T ----
    floatx4 s[4];
    #pragma unroll
    for (int jt = 0; jt < 4; ++jt) {
      floatx4 z = (floatx4){0.f, 0.f, 0.f, 0.f};
      z = __builtin_amdgcn_mfma_f32_16x16x32_f16(k[2 * jt], bq0, z, 0, 0, 0);
      s[jt] = __builtin_amdgcn_mfma_f32_16x16x32_f16(k[2 * jt + 1], bq1, z, 0, 0, 0);
    }
    // ---- V^T A-frags: issued here, consumed after softmax (latency hidden) ----
    half4 v[16];
    #pragma unroll
    for (int dt = 0; dt < 4; ++dt)
      #pragma unroll
      for (int jt = 0; jt < 4; ++jt)
        v[dt * 4 + jt] =
            *(const half4*)(Vp + (size_t)(dt * 16 + ln) * S_LEN + c + jt * 16 + quad * 4);
    // ---- mask + scale (exp2 domain); j=0 always excluded (handled in init) ----
    const bool full_in = (c != 0) && (c >= qw - 241) && (c <= qw + 193);
    if (full_in) {
      #pragma unroll
      for (int jt = 0; jt < 4; ++jt)
        #pragma unroll
        for (int r = 0; r < 4; ++r) s[jt][r] *= SC2;
    } else {
      const int q = qw + ln;
      #pragma unroll
      for (int jt = 0; jt < 4; ++jt) {
        #pragma unroll
        for (int r = 0; r < 4; ++r) {
          int j = c + jt * 16 + quad * 4 + r;
          int d = q - j;
          bool ok = (d <= WIN && d >= -WIN) && (j != 0);
          s[jt][r] = ok ? s[jt][r] * SC2 : -3.0e38f;
        }
      }
    }
    // ---- online softmax over j (per-lane fold + 2 shfl over quad) ----
    float mx = fmaxf(fmaxf(fmaxf(s[0][0], s[0][1]), fmaxf(s[0][2], s[0][3])),
                     fmaxf(fmaxf(s[1][0], s[1][1]), fmaxf(s[1][2], s[1][3])));
    mx = fmaxf(mx, fmaxf(fmaxf(fmaxf(s[2][0], s[2][1]), fmaxf(s[2][2], s[2][3])),
                         fmaxf(fmaxf(s[3][0], s[3][1]), fmaxf(s[3][2], s[3][3]))));
    mx = fmaxf(mx, __shfl_xor(mx, 16, 64));
    mx = fmaxf(mx, __shfl_xor(mx, 32, 64));
    float mnew = fmaxf(m_i, mx);
    float alpha = exp2f(m_i - mnew);
    m_i = mnew;

    half4 Pt[4];  // == B-frag of 16x16x16f16 directly
    float ss = 0.f;
    #pragma unroll
    for (int jt = 0; jt < 4; ++jt) {
      #pragma unroll
      for (int r = 0; r < 4; ++r) {
        float pe = exp2f(s[jt][r] - mnew);
        Pt[jt][r] = (fp16)pe;
        ss += pe;
      }
    }
    ss += __shfl_xor(ss, 16, 64);
    ss += __shfl_xor(ss, 32, 64);
    l_i = l_i * alpha + ss;

    #pragma unroll
    for (int dt = 0; dt < 4; ++dt)
      #pragma unroll
      for (int r = 0; r < 4; ++r) acc[dt][r] *= alpha;

    // ---- O^T += V^T P^T ----
    #pragma unroll
    for (int dt = 0; dt < 4; ++dt)
      #pragma unroll
      for (int jt = 0; jt < 4; ++jt)
        acc[dt] = __builtin_amdgcn_mfma_f32_16x16x16f16(v[dt * 4 + jt], Pt[jt], acc[dt], 0, 0, 0);
  };

  int cs = qw - WIN; if (cs < 0) cs = 0; cs &= ~63;
  int ce = qw + 15 + WIN + 1; if (ce > S_LEN) ce = S_LEN; else ce = (ce + 63) & ~63;

  // ---- K-prefetch pipelined loop (double-buffered, manually unrolled x2) ----
  half8 kA[8], kB[8];
  int c = cs;
  loadK(c, kA);
  for (;;) {
    int cn = c + 64;
    if (cn >= ce) { body(c, kA); break; }
    loadK(cn, kB);
    body(c, kA);
    c = cn; cn += 64;
    if (cn >= ce) { body(c, kB); break; }
    loadK(cn, kA);
    body(c, kB);
    c = cn;
  }

  // ---- epilogue: normalize + write bf16 [b][q][h*64+d]; skip row 0 ----
  const float inv = 1.0f / l_i;
  const int q = qw + ln;
  if (q != 0) {
    #pragma unroll
    for (int dt = 0; dt < 4; ++dt) {
      ushort4 pk;
      pk.x = f2b(acc[dt][0] * inv);
      pk.y = f2b(acc[dt][1] * inv);
      pk.z = f2b(acc[dt][2] * inv);
      pk.w = f2b(acc[dt][3] * inv);
      *(ushort4*)&aout[(size_t)(b * S_LEN + q) * DM + h * DH + dt * 16 + quad * 4] = pk;
    }
  }
}

// ---------- launch ----------
extern "C" void kernel_launch(void* const* d_in, const int* in_sizes, int n_in,
                              void* d_out, int out_size, void* d_ws, size_t ws_size,
                              hipStream_t stream) {
  const float* x  = (const float*)d_in[0];
  const float* Wq = (const float*)d_in[1];
  const float* bq = (const float*)d_in[2];
  const float* Wk = (const float*)d_in[3];
  const float* bk = (const float*)d_in[4];
  const float* Wv = (const float*)d_in[5];
  const float* bv = (const float*)d_in[6];
  const float* Wo = (const float*)d_in[7];
  const float* bo = (const float*)d_in[8];
  float* out = (float*)d_out;

  const size_t SEG = (size_t)4096 * 1024;
  bf16* xb = (bf16*)d_ws;
  bf16* wT = xb + SEG;
  fp16* Qh = (fp16*)(wT + SEG);
  fp16* Kh = Qh + SEG;
  fp16* Vt = Kh + SEG;   // [bh][d][s]
  bf16* ao = (bf16*)(Vt + SEG);

  k_convert_x<<<dim3(4096), dim3(256), 0, stream>>>((const float4*)x, (ushort4*)xb);
  k_transpose_cvt<<<dim3(32, 32, 4), dim3(32, 8), 0, stream>>>(Wq, Wk, Wv, Wo, wT);
  k_gemm<0><<<dim3(24, 32), dim3(256), 0, stream>>>(xb, wT, bq, bk, bv, Qh, Kh, Vt, nullptr);
  k_attn<<<dim3(129, 32), dim3(64), 0, stream>>>(Qh, Kh, Vt, ao);
  k_gemm<1><<<dim3(8, 32), dim3(256), 0, stream>>>(ao, wT + (size_t)3 * 1024 * 1024, bo,
                                                   nullptr, nullptr, nullptr, nullptr, nullptr, out);
}

// Round 6
// 274.116 us; speedup vs baseline: 1.3607x; 1.3607x over previous
//
#include <hip/hip_runtime.h>
#include <hip/hip_bf16.h>

typedef __attribute__((ext_vector_type(8))) short short8;
typedef __attribute__((ext_vector_type(4))) float floatx4;
typedef __attribute__((ext_vector_type(8))) _Float16 half8;
typedef __attribute__((ext_vector_type(4))) _Float16 half4;

using bf16 = __hip_bfloat16;
using fp16 = _Float16;

#define S_LEN 2048
#define DM 1024
#define NH 16
#define DH 64
#define WIN 256

// ---------- helpers ----------
__device__ __forceinline__ unsigned short f2b(float f) {
  __hip_bfloat16 h = __float2bfloat16(f);
  return *reinterpret_cast<unsigned short*>(&h);
}
__device__ __forceinline__ unsigned short f2h(float f) {
  fp16 h = (fp16)f;
  return *reinterpret_cast<unsigned short*>(&h);
}
__device__ __forceinline__ void lds_load16(void* lds, const void* gptr) {
  __builtin_amdgcn_global_load_lds(
      (const __attribute__((address_space(1))) unsigned int*)gptr,
      (__attribute__((address_space(3))) unsigned int*)lds, 16, 0, 0);
}

// ---------- K1: x fp32 -> bf16 ----------
__global__ __launch_bounds__(256) void k_convert_x(const float4* __restrict__ in,
                                                   ushort4* __restrict__ out) {
  int i = blockIdx.x * 256 + threadIdx.x;
  float4 v = in[i];
  ushort4 r;
  r.x = f2b(v.x); r.y = f2b(v.y); r.z = f2b(v.z); r.w = f2b(v.w);
  out[i] = r;
}

// ---------- K2: W[k][n] fp32 -> Wt[n][k] bf16 (4 matrices) ----------
__global__ __launch_bounds__(256) void k_transpose_cvt(const float* __restrict__ W0,
                                                       const float* __restrict__ W1,
                                                       const float* __restrict__ W2,
                                                       const float* __restrict__ W3,
                                                       bf16* __restrict__ out) {
  __shared__ float t[32][33];
  const float* W = (blockIdx.z == 0) ? W0 : (blockIdx.z == 1) ? W1 : (blockIdx.z == 2) ? W2 : W3;
  bf16* O = out + (size_t)blockIdx.z * 1024 * 1024;
  int x0 = blockIdx.x * 32, y0 = blockIdx.y * 32;
  int tx = threadIdx.x, ty = threadIdx.y;  // block (32,8)
  #pragma unroll
  for (int i = 0; i < 32; i += 8) t[ty + i][tx] = W[(size_t)(y0 + ty + i) * 1024 + x0 + tx];
  __syncthreads();
  #pragma unroll
  for (int i = 0; i < 32; i += 8)
    O[(size_t)(x0 + ty + i) * 1024 + y0 + tx] = __float2bfloat16(t[tx][ty + i]);
}

// ---------- K3/K5: bf16 MFMA GEMM, C = A[M][1024] * Bt[N][1024]^T ----------
// MODE 0: N=3072 (Wq|Wk|Wv) -> Qh/Kh [bh][s][64] fp16; V transposed: Vt [bh][d][s] fp16
// MODE 1: N=1024 (Wo) -> fp32 [m][1024]
template <int MODE>
__global__ __launch_bounds__(256) void k_gemm(const bf16* __restrict__ A,
                                              const bf16* __restrict__ Bt,
                                              const float* __restrict__ bias_q,
                                              const float* __restrict__ bias_k,
                                              const float* __restrict__ bias_v,
                                              fp16* __restrict__ Qh, fp16* __restrict__ Kh,
                                              fp16* __restrict__ Vt, float* __restrict__ outF) {
  __shared__ __align__(16) bf16 As[128 * 32];
  __shared__ __align__(16) bf16 Bs[128 * 32];
  const int tid = threadIdx.x;
  const int wave = tid >> 6, lane = tid & 63;
  const int m0 = blockIdx.y * 128, n0 = blockIdx.x * 128;
  const int r0 = tid >> 2;
  const int cb = (tid & 3) * 16;
  const char* Ag = (const char*)A + (size_t)(m0 + r0) * 2048 + cb;
  const char* Bg = (const char*)Bt + (size_t)(n0 + r0) * 2048 + cb;
  char* AsW0 = (char*)As + wave * 1024;
  char* AsW1 = (char*)As + 4096 + wave * 1024;
  char* BsW0 = (char*)Bs + wave * 1024;
  char* BsW1 = (char*)Bs + 4096 + wave * 1024;
  const int wm = (wave & 1) * 64, wn = (wave >> 1) * 64;
  const int ln = lane & 15, quad = lane >> 4;

  floatx4 acc[4][4];
  #pragma unroll
  for (int i = 0; i < 4; i++)
    #pragma unroll
    for (int j = 0; j < 4; j++) acc[i][j] = (floatx4){0.f, 0.f, 0.f, 0.f};

  for (int k0 = 0; k0 < 1024; k0 += 32) {
    __syncthreads();
    lds_load16(AsW0, Ag + k0 * 2);
    lds_load16(AsW1, Ag + 64 * 2048 + k0 * 2);
    lds_load16(BsW0, Bg + k0 * 2);
    lds_load16(BsW1, Bg + 64 * 2048 + k0 * 2);
    __syncthreads();
    short8 af[4], bfr[4];
    #pragma unroll
    for (int mi = 0; mi < 4; mi++)
      af[mi] = *(const short8*)&As[(wm + mi * 16 + ln) * 32 + quad * 8];
    #pragma unroll
    for (int ni = 0; ni < 4; ni++)
      bfr[ni] = *(const short8*)&Bs[(wn + ni * 16 + ln) * 32 + quad * 8];
    #pragma unroll
    for (int mi = 0; mi < 4; mi++)
      #pragma unroll
      for (int ni = 0; ni < 4; ni++)
        acc[mi][ni] = __builtin_amdgcn_mfma_f32_16x16x32_bf16(af[mi], bfr[ni], acc[mi][ni], 0, 0, 0);
  }

  if constexpr (MODE == 0) {
    #pragma unroll
    for (int ni = 0; ni < 4; ni++) {
      int n = n0 + wn + ni * 16 + ln;  // 0..3071; g uniform across the wave
      int g = n >> 10, nn = n & 1023;
      int h = nn >> 6, dd = nn & 63;
      if (g == 2) {  // V -> Vt[bh][d][s] fp16, 4 consecutive s per 8B store
        float bias = bias_v[nn];
        #pragma unroll
        for (int mi = 0; mi < 4; mi++) {
          int m = m0 + wm + mi * 16 + quad * 4;
          int b = m >> 11, s = m & 2047;
          ushort4 pk;
          pk.x = f2h(acc[mi][ni][0] + bias);
          pk.y = f2h(acc[mi][ni][1] + bias);
          pk.z = f2h(acc[mi][ni][2] + bias);
          pk.w = f2h(acc[mi][ni][3] + bias);
          *(ushort4*)&Vt[((size_t)(b * NH + h) * DH + dd) * S_LEN + s] = pk;
        }
      } else {
        const float* bp = (g == 0) ? bias_q : bias_k;
        fp16* og = (g == 0) ? Qh : Kh;
        float bias = bp[nn];
        #pragma unroll
        for (int mi = 0; mi < 4; mi++) {
          #pragma unroll
          for (int r = 0; r < 4; r++) {
            int m = m0 + wm + mi * 16 + quad * 4 + r;
            int b = m >> 11, s = m & 2047;
            og[(size_t)((b * NH + h) * S_LEN + s) * DH + dd] = (fp16)(acc[mi][ni][r] + bias);
          }
        }
      }
    }
  } else {
    #pragma unroll
    for (int ni = 0; ni < 4; ni++) {
      int n = n0 + wn + ni * 16 + ln;
      float bias = bias_q[n];
      #pragma unroll
      for (int mi = 0; mi < 4; mi++)
        #pragma unroll
        for (int r = 0; r < 4; r++) {
          int m = m0 + wm + mi * 16 + quad * 4 + r;
          outF[(size_t)m * 1024 + n] = acc[mi][ni][r] + bias;
        }
    }
  }
}

// ---------- K4: fixed-max register-resident MFMA flash attention ----------
// 1D grid 1056, 256 threads. XCD-affinity swizzle: i&7 -> xcd, 4 bh per xcd
// (K+V of 4 bh = 2MB fits one XCD's 4MB L2). tile<32: 64-q window tile,
// 4 waves x 16 q; S^T trick (P in regs), K double-buffered, fixed softmax
// max m=8 (inputs bounded: |logit*log2e| < 4 by Cauchy-Schwarz) => NO
// cross-lane reductions in the loop. tile==32: full-softmax row q=0.
__global__ __launch_bounds__(256, 2) void k_attn(const fp16* __restrict__ Qh,
                                                 const fp16* __restrict__ Kh,
                                                 const fp16* __restrict__ Vt,
                                                 bf16* __restrict__ aout) {
  const int i = blockIdx.x;
  const int xcd = i & 7, rr = i >> 3;
  const int bh = xcd * 4 + (rr & 3);
  const int tile = rr >> 2;  // 0..32
  const int b = bh >> 4, h = bh & 15;
  const size_t base = (size_t)bh * S_LEN * DH;
  const fp16* Qp = Qh + base;
  const fp16* Kp = Kh + base;
  const fp16* Vp = Vt + base;  // [d][s]
  const float SC2 = 0.18033688011112042f;  // 0.125 * log2(e)

  if (tile == 32) {
    // ===== global query row q=0: softmax over ALL 2048 keys, 4 waves =====
    __shared__ float sP[2048];
    __shared__ float red[4];
    __shared__ float oR[256];
    const int t = threadIdx.x, wv = t >> 6, lane = t & 63;
    const int g = lane >> 3, e8 = lane & 7;
    const half8 q0t = *(const half8*)(Qp + e8 * 8);
    float lsum = 0.f;
    for (int it = 0; it < 64; ++it) {
      int grp = wv * 64 + it;  // key j = grp*8 + g
      const half8 kv = *(const half8*)(Kp + (size_t)(grp * 8 + g) * DH + e8 * 8);
      float p = 0.f;
      #pragma unroll
      for (int e = 0; e < 8; ++e) p += (float)q0t[e] * (float)kv[e];
      p += __shfl_xor(p, 1, 64);
      p += __shfl_xor(p, 2, 64);
      p += __shfl_xor(p, 4, 64);
      p = exp2f(fmaf(p, SC2, -8.f));
      if (e8 == 0) sP[grp * 8 + g] = p;
      lsum += p;  // 8x duplicated; divide later
    }
    #pragma unroll
    for (int off = 1; off < 64; off <<= 1) lsum += __shfl_xor(lsum, off, 64);
    if (lane == 0) red[wv] = lsum;
    __syncthreads();
    const float ltot = (red[0] + red[1] + red[2] + red[3]) * 0.125f;
    const int d = t & 63, qu = t >> 6;
    float o = 0.f;
    for (int j0 = qu * 512; j0 < qu * 512 + 512; j0 += 8) {
      half8 vv = *(const half8*)(Vp + (size_t)d * S_LEN + j0);
      #pragma unroll
      for (int e = 0; e < 8; ++e) o += sP[j0 + e] * (float)vv[e];
    }
    oR[t] = o;
    __syncthreads();
    if (t < 64) {
      float oo = oR[t] + oR[t + 64] + oR[t + 128] + oR[t + 192];
      aout[(size_t)(b * S_LEN) * DM + h * DH + t] = __float2bfloat16(oo / ltot);
    }
    return;
  }

  // ===== window tiles: 4 waves x 16 queries =====
  const int tid = threadIdx.x;
  const int w = tid >> 6, lane = tid & 63;
  const int ln = lane & 15, quad = lane >> 4;
  const int qw = tile * 64 + w * 16;

  const half8 bq0 = *(const half8*)(Qp + (size_t)(qw + ln) * DH + quad * 8);
  const half8 bq1 = *(const half8*)(Qp + (size_t)(qw + ln) * DH + 32 + quad * 8);

  floatx4 acc[4];  // O^T tiles: d = dt*16+quad*4+r, col q = ln
  float l_i;       // per-lane partial sum of p over this lane's j slots

  // ---- init: fold global key j=0 (p0 broadcast to all lanes after shfls) ----
  {
    const half8 k0a = *(const half8*)(Kp + quad * 8);
    const half8 k0b = *(const half8*)(Kp + 32 + quad * 8);
    float s0 = 0.f;
    #pragma unroll
    for (int e = 0; e < 8; ++e)
      s0 += (float)bq0[e] * (float)k0a[e] + (float)bq1[e] * (float)k0b[e];
    s0 += __shfl_xor(s0, 16, 64);
    s0 += __shfl_xor(s0, 32, 64);
    float p0 = exp2f(fmaf(s0, SC2, -8.f));
    l_i = (quad == 0) ? p0 : 0.f;  // count j=0 once per q row
    #pragma unroll
    for (int dt = 0; dt < 4; ++dt)
      #pragma unroll
      for (int r = 0; r < 4; ++r)
        acc[dt][r] = p0 * (float)Vp[(size_t)(dt * 16 + quad * 4 + r) * S_LEN];
  }

  auto loadK = [&](int c, half8* k) {
    #pragma unroll
    for (int jt = 0; jt < 4; ++jt) {
      const fp16* kr = Kp + (size_t)(c + jt * 16 + ln) * DH;
      k[2 * jt]     = *(const half8*)(kr + quad * 8);
      k[2 * jt + 1] = *(const half8*)(kr + 32 + quad * 8);
    }
  };

  auto body = [&](int c, const half8* k) {
    // V^T A-frags: issued first, consumed last (latency hidden)
    half4 v[16];
    #pragma unroll
    for (int dt = 0; dt < 4; ++dt)
      #pragma unroll
      for (int jt = 0; jt < 4; ++jt)
        v[dt * 4 + jt] =
            *(const half4*)(Vp + (size_t)(dt * 16 + ln) * S_LEN + c + jt * 16 + quad * 4);
    // S^T = K Q^T
    floatx4 s[4];
    #pragma unroll
    for (int jt = 0; jt < 4; ++jt) {
      floatx4 z = (floatx4){0.f, 0.f, 0.f, 0.f};
      z = __builtin_amdgcn_mfma_f32_16x16x32_f16(k[2 * jt], bq0, z, 0, 0, 0);
      s[jt] = __builtin_amdgcn_mfma_f32_16x16x32_f16(k[2 * jt + 1], bq1, z, 0, 0, 0);
    }
    // p = 2^(s*SC2 - 8); mask; accumulate l per-lane; P == PV B-frag directly
    const bool full_in = (c != 0) && (c >= qw - 241) && (c <= qw + 193);
    half4 Pt[4];
    if (full_in) {
      #pragma unroll
      for (int jt = 0; jt < 4; ++jt)
        #pragma unroll
        for (int r = 0; r < 4; ++r) {
          float pe = exp2f(fmaf(s[jt][r], SC2, -8.f));
          Pt[jt][r] = (fp16)pe;
          l_i += pe;
        }
    } else {
      const int q = qw + ln;
      #pragma unroll
      for (int jt = 0; jt < 4; ++jt) {
        #pragma unroll
        for (int r = 0; r < 4; ++r) {
          int j = c + jt * 16 + quad * 4 + r;
          int dq = q - j;
          bool ok = (dq <= WIN && dq >= -WIN) && (j != 0);
          float pe = ok ? exp2f(fmaf(s[jt][r], SC2, -8.f)) : 0.f;
          Pt[jt][r] = (fp16)pe;
          l_i += pe;
        }
      }
    }
    // O^T += V^T P^T
    #pragma unroll
    for (int dt = 0; dt < 4; ++dt)
      #pragma unroll
      for (int jt = 0; jt < 4; ++jt)
        acc[dt] = __builtin_amdgcn_mfma_f32_16x16x16f16(v[dt * 4 + jt], Pt[jt], acc[dt], 0, 0, 0);
  };

  int cs = qw - WIN; if (cs < 0) cs = 0; cs &= ~63;
  int ce = qw + 15 + WIN + 1; if (ce > S_LEN) ce = S_LEN; else ce = (ce + 63) & ~63;

  // K-prefetch pipelined loop (double-buffered, manually unrolled x2)
  half8 kA[8], kB[8];
  int c = cs;
  loadK(c, kA);
  for (;;) {
    int cn = c + 64;
    if (cn >= ce) { body(c, kA); break; }
    loadK(cn, kB);
    body(c, kA);
    c = cn; cn += 64;
    if (cn >= ce) { body(c, kB); break; }
    loadK(cn, kA);
    body(c, kB);
    c = cn;
  }

  // epilogue: reduce l over quads (only cross-lane op), normalize, store
  float lt = l_i;
  lt += __shfl_xor(lt, 16, 64);
  lt += __shfl_xor(lt, 32, 64);
  const float inv = 1.0f / lt;
  const int q = qw + ln;
  if (q != 0) {  // row 0 handled by the tile==32 block
    #pragma unroll
    for (int dt = 0; dt < 4; ++dt) {
      ushort4 pk;
      pk.x = f2b(acc[dt][0] * inv);
      pk.y = f2b(acc[dt][1] * inv);
      pk.z = f2b(acc[dt][2] * inv);
      pk.w = f2b(acc[dt][3] * inv);
      *(ushort4*)&aout[(size_t)(b * S_LEN + q) * DM + h * DH + dt * 16 + quad * 4] = pk;
    }
  }
}

// ---------- launch ----------
extern "C" void kernel_launch(void* const* d_in, const int* in_sizes, int n_in,
                              void* d_out, int out_size, void* d_ws, size_t ws_size,
                              hipStream_t stream) {
  const float* x  = (const float*)d_in[0];
  const float* Wq = (const float*)d_in[1];
  const float* bq = (const float*)d_in[2];
  const float* Wk = (const float*)d_in[3];
  const float* bk = (const float*)d_in[4];
  const float* Wv = (const float*)d_in[5];
  const float* bv = (const float*)d_in[6];
  const float* Wo = (const float*)d_in[7];
  const float* bo = (const float*)d_in[8];
  float* out = (float*)d_out;

  const size_t SEG = (size_t)4096 * 1024;
  bf16* xb = (bf16*)d_ws;
  bf16* wT = xb + SEG;
  fp16* Qh = (fp16*)(wT + SEG);
  fp16* Kh = Qh + SEG;
  fp16* Vt = Kh + SEG;   // [bh][d][s]
  bf16* ao = (bf16*)(Vt + SEG);

  k_convert_x<<<dim3(4096), dim3(256), 0, stream>>>((const float4*)x, (ushort4*)xb);
  k_transpose_cvt<<<dim3(32, 32, 4), dim3(32, 8), 0, stream>>>(Wq, Wk, Wv, Wo, wT);
  k_gemm<0><<<dim3(24, 32), dim3(256), 0, stream>>>(xb, wT, bq, bk, bv, Qh, Kh, Vt, nullptr);
  k_attn<<<dim3(1056), dim3(256), 0, stream>>>(Qh, Kh, Vt, ao);
  k_gemm<1><<<dim3(8, 32), dim3(256), 0, stream>>>(ao, wT + (size_t)3 * 1024 * 1024, bo,
                                                   nullptr, nullptr, nullptr, nullptr, nullptr, out);
}

// Round 7
// 207.876 us; speedup vs baseline: 1.7943x; 1.3187x over previous
//
#include <hip/hip_runtime.h>
#include <hip/hip_bf16.h>

typedef __attribute__((ext_vector_type(8))) short short8;
typedef __attribute__((ext_vector_type(4))) float floatx4;
typedef __attribute__((ext_vector_type(8))) _Float16 half8;
typedef __attribute__((ext_vector_type(4))) _Float16 half4;

using bf16 = __hip_bfloat16;
using fp16 = _Float16;

#define S_LEN 2048
#define DM 1024
#define NH 16
#define DH 64
#define WIN 256

// ---------- helpers ----------
__device__ __forceinline__ unsigned short f2b(float f) {
  __hip_bfloat16 h = __float2bfloat16(f);
  return *reinterpret_cast<unsigned short*>(&h);
}
__device__ __forceinline__ unsigned short f2h(float f) {
  fp16 h = (fp16)f;
  return *reinterpret_cast<unsigned short*>(&h);
}
__device__ __forceinline__ void lds_load16(void* lds, const void* gptr) {
  __builtin_amdgcn_global_load_lds(
      (const __attribute__((address_space(1))) unsigned int*)gptr,
      (__attribute__((address_space(3))) unsigned int*)lds, 16, 0, 0);
}

// ---------- K1: x fp32 -> bf16 ----------
__global__ __launch_bounds__(256) void k_convert_x(const float4* __restrict__ in,
                                                   ushort4* __restrict__ out) {
  int i = blockIdx.x * 256 + threadIdx.x;
  float4 v = in[i];
  ushort4 r;
  r.x = f2b(v.x); r.y = f2b(v.y); r.z = f2b(v.z); r.w = f2b(v.w);
  out[i] = r;
}

// ---------- K2: W[k][n] fp32 -> Wt[n][k] bf16 (4 matrices) ----------
__global__ __launch_bounds__(256) void k_transpose_cvt(const float* __restrict__ W0,
                                                       const float* __restrict__ W1,
                                                       const float* __restrict__ W2,
                                                       const float* __restrict__ W3,
                                                       bf16* __restrict__ out) {
  __shared__ float t[32][33];
  const float* W = (blockIdx.z == 0) ? W0 : (blockIdx.z == 1) ? W1 : (blockIdx.z == 2) ? W2 : W3;
  bf16* O = out + (size_t)blockIdx.z * 1024 * 1024;
  int x0 = blockIdx.x * 32, y0 = blockIdx.y * 32;
  int tx = threadIdx.x, ty = threadIdx.y;  // block (32,8)
  #pragma unroll
  for (int i = 0; i < 32; i += 8) t[ty + i][tx] = W[(size_t)(y0 + ty + i) * 1024 + x0 + tx];
  __syncthreads();
  #pragma unroll
  for (int i = 0; i < 32; i += 8)
    O[(size_t)(x0 + ty + i) * 1024 + y0 + tx] = __float2bfloat16(t[tx][ty + i]);
}

// ---------- K3/K5: bf16 MFMA GEMM, C = A[M][1024] * Bt[N][1024]^T ----------
// MODE 0: N=3072 (Wq|Wk|Wv) -> Qh/Kh [bh][s][64] fp16; V transposed: Vt [bh][d][s] fp16
// MODE 1: N=1024 (Wo) -> fp32 [m][1024]
template <int MODE>
__global__ __launch_bounds__(256) void k_gemm(const bf16* __restrict__ A,
                                              const bf16* __restrict__ Bt,
                                              const float* __restrict__ bias_q,
                                              const float* __restrict__ bias_k,
                                              const float* __restrict__ bias_v,
                                              fp16* __restrict__ Qh, fp16* __restrict__ Kh,
                                              fp16* __restrict__ Vt, float* __restrict__ outF) {
  __shared__ __align__(16) bf16 As[128 * 32];
  __shared__ __align__(16) bf16 Bs[128 * 32];
  const int tid = threadIdx.x;
  const int wave = tid >> 6, lane = tid & 63;
  const int m0 = blockIdx.y * 128, n0 = blockIdx.x * 128;
  const int r0 = tid >> 2;
  const int cb = (tid & 3) * 16;
  const char* Ag = (const char*)A + (size_t)(m0 + r0) * 2048 + cb;
  const char* Bg = (const char*)Bt + (size_t)(n0 + r0) * 2048 + cb;
  char* AsW0 = (char*)As + wave * 1024;
  char* AsW1 = (char*)As + 4096 + wave * 1024;
  char* BsW0 = (char*)Bs + wave * 1024;
  char* BsW1 = (char*)Bs + 4096 + wave * 1024;
  const int wm = (wave & 1) * 64, wn = (wave >> 1) * 64;
  const int ln = lane & 15, quad = lane >> 4;

  floatx4 acc[4][4];
  #pragma unroll
  for (int i = 0; i < 4; i++)
    #pragma unroll
    for (int j = 0; j < 4; j++) acc[i][j] = (floatx4){0.f, 0.f, 0.f, 0.f};

  for (int k0 = 0; k0 < 1024; k0 += 32) {
    __syncthreads();
    lds_load16(AsW0, Ag + k0 * 2);
    lds_load16(AsW1, Ag + 64 * 2048 + k0 * 2);
    lds_load16(BsW0, Bg + k0 * 2);
    lds_load16(BsW1, Bg + 64 * 2048 + k0 * 2);
    __syncthreads();
    short8 af[4], bfr[4];
    #pragma unroll
    for (int mi = 0; mi < 4; mi++)
      af[mi] = *(const short8*)&As[(wm + mi * 16 + ln) * 32 + quad * 8];
    #pragma unroll
    for (int ni = 0; ni < 4; ni++)
      bfr[ni] = *(const short8*)&Bs[(wn + ni * 16 + ln) * 32 + quad * 8];
    #pragma unroll
    for (int mi = 0; mi < 4; mi++)
      #pragma unroll
      for (int ni = 0; ni < 4; ni++)
        acc[mi][ni] = __builtin_amdgcn_mfma_f32_16x16x32_bf16(af[mi], bfr[ni], acc[mi][ni], 0, 0, 0);
  }

  if constexpr (MODE == 0) {
    #pragma unroll
    for (int ni = 0; ni < 4; ni++) {
      int n = n0 + wn + ni * 16 + ln;  // 0..3071; g uniform across the wave
      int g = n >> 10, nn = n & 1023;
      int h = nn >> 6, dd = nn & 63;
      if (g == 2) {  // V -> Vt[bh][d][s] fp16, 4 consecutive s per 8B store
        float bias = bias_v[nn];
        #pragma unroll
        for (int mi = 0; mi < 4; mi++) {
          int m = m0 + wm + mi * 16 + quad * 4;
          int b = m >> 11, s = m & 2047;
          ushort4 pk;
          pk.x = f2h(acc[mi][ni][0] + bias);
          pk.y = f2h(acc[mi][ni][1] + bias);
          pk.z = f2h(acc[mi][ni][2] + bias);
          pk.w = f2h(acc[mi][ni][3] + bias);
          *(ushort4*)&Vt[((size_t)(b * NH + h) * DH + dd) * S_LEN + s] = pk;
        }
      } else {
        const float* bp = (g == 0) ? bias_q : bias_k;
        fp16* og = (g == 0) ? Qh : Kh;
        float bias = bp[nn];
        #pragma unroll
        for (int mi = 0; mi < 4; mi++) {
          #pragma unroll
          for (int r = 0; r < 4; r++) {
            int m = m0 + wm + mi * 16 + quad * 4 + r;
            int b = m >> 11, s = m & 2047;
            og[(size_t)((b * NH + h) * S_LEN + s) * DH + dd] = (fp16)(acc[mi][ni][r] + bias);
          }
        }
      }
    }
  } else {
    #pragma unroll
    for (int ni = 0; ni < 4; ni++) {
      int n = n0 + wn + ni * 16 + ln;
      float bias = bias_q[n];
      #pragma unroll
      for (int mi = 0; mi < 4; mi++)
        #pragma unroll
        for (int r = 0; r < 4; r++) {
          int m = m0 + wm + mi * 16 + quad * 4 + r;
          outF[(size_t)m * 1024 + n] = acc[mi][ni][r] + bias;
        }
    }
  }
}

// ---------- K4: LDS-staged double-buffered MFMA flash attention ----------
// 1D grid 1056, 256 thr. XCD swizzle (4 bh per XCD -> L2-resident K/V).
// Per block: 64-q tile; K chunk [64][64] + V^T chunk [64][64] staged to LDS
// (coalesced uint4 loads, padded rows of 72 halfs -> frag reads at bank floor).
// Hand cp.async: load c+1 -> compute c (from LDS) -> ds_write c+1 -> barrier.
// S^T trick (P in regs), fixed-max softmax (no cross-lane ops in loop),
// j=0 folded into init, q=0 row in dedicated tile==32 blocks.
__global__ __launch_bounds__(256, 4) void k_attn(const fp16* __restrict__ Qh,
                                                 const fp16* __restrict__ Kh,
                                                 const fp16* __restrict__ Vt,
                                                 bf16* __restrict__ aout) {
  __shared__ __align__(16) fp16 KsL[2][64 * 72];
  __shared__ __align__(16) fp16 VsL[2][64 * 72];

  const int i = blockIdx.x;
  const int xcd = i & 7, rr = i >> 3;
  const int bh = xcd * 4 + (rr & 3);
  const int tile = rr >> 2;  // 0..32
  const int b = bh >> 4, h = bh & 15;
  const size_t base = (size_t)bh * S_LEN * DH;
  const fp16* Qp = Qh + base;
  const fp16* Kp = Kh + base;
  const fp16* Vp = Vt + base;  // [d][s]
  const float SC2 = 0.18033688011112042f;  // 0.125 * log2(e)
  const int tid = threadIdx.x;

  if (tile == 32) {
    // ===== global query row q=0: softmax over ALL 2048 keys, 4 waves =====
    float* sP = (float*)&KsL[0][0];       // 8KB
    float* oR = (float*)&VsL[0][0];       // 1KB
    float* red = (float*)&VsL[1][0];      // 16B
    const int wv = tid >> 6, lane = tid & 63;
    const int g = lane >> 3, e8 = lane & 7;
    const half8 q0t = *(const half8*)(Qp + e8 * 8);
    float lsum = 0.f;
    for (int it = 0; it < 64; ++it) {
      int grp = wv * 64 + it;  // key j = grp*8 + g
      const half8 kv = *(const half8*)(Kp + (size_t)(grp * 8 + g) * DH + e8 * 8);
      float p = 0.f;
      #pragma unroll
      for (int e = 0; e < 8; ++e) p += (float)q0t[e] * (float)kv[e];
      p += __shfl_xor(p, 1, 64);
      p += __shfl_xor(p, 2, 64);
      p += __shfl_xor(p, 4, 64);
      p = exp2f(fmaf(p, SC2, -8.f));
      if (e8 == 0) sP[grp * 8 + g] = p;
      lsum += p;  // 8x duplicated; divide later
    }
    #pragma unroll
    for (int off = 1; off < 64; off <<= 1) lsum += __shfl_xor(lsum, off, 64);
    if (lane == 0) red[wv] = lsum;
    __syncthreads();
    const float ltot = (red[0] + red[1] + red[2] + red[3]) * 0.125f;
    const int d = tid & 63, qu = tid >> 6;
    float o = 0.f;
    for (int j0 = qu * 512; j0 < qu * 512 + 512; j0 += 8) {
      half8 vv = *(const half8*)(Vp + (size_t)d * S_LEN + j0);
      #pragma unroll
      for (int e = 0; e < 8; ++e) o += sP[j0 + e] * (float)vv[e];
    }
    oR[tid] = o;
    __syncthreads();
    if (tid < 64) {
      float oo = oR[tid] + oR[tid + 64] + oR[tid + 128] + oR[tid + 192];
      aout[(size_t)(b * S_LEN) * DM + h * DH + tid] = __float2bfloat16(oo / ltot);
    }
    return;
  }

  // ===== window tiles: 4 waves x 16 queries, block covers 64 q =====
  const int w = tid >> 6, lane = tid & 63;
  const int ln = lane & 15, quad = lane >> 4;
  const int qb = tile * 64;
  const int qw = qb + w * 16;

  const half8 bq0 = *(const half8*)(Qp + (size_t)(qw + ln) * DH + quad * 8);
  const half8 bq1 = *(const half8*)(Qp + (size_t)(qw + ln) * DH + 32 + quad * 8);

  floatx4 acc[4];  // O^T tiles: d = dt*16+quad*4+r, col q = ln
  float l_i;

  // ---- init: fold global key j=0 (p0 broadcast after shfls) ----
  {
    const half8 k0a = *(const half8*)(Kp + quad * 8);
    const half8 k0b = *(const half8*)(Kp + 32 + quad * 8);
    float s0 = 0.f;
    #pragma unroll
    for (int e = 0; e < 8; ++e)
      s0 += (float)bq0[e] * (float)k0a[e] + (float)bq1[e] * (float)k0b[e];
    s0 += __shfl_xor(s0, 16, 64);
    s0 += __shfl_xor(s0, 32, 64);
    float p0 = exp2f(fmaf(s0, SC2, -8.f));
    l_i = (quad == 0) ? p0 : 0.f;  // count j=0 once per q row
    #pragma unroll
    for (int dt = 0; dt < 4; ++dt)
      #pragma unroll
      for (int r = 0; r < 4; ++r)
        acc[dt][r] = p0 * (float)Vp[(size_t)(dt * 16 + quad * 4 + r) * S_LEN];
  }

  // ---- block-uniform chunk range ----
  int cs = qb - WIN; if (cs < 0) cs = 0;                 // 64-aligned already
  int ce = qb + 64 + WIN; if (ce > S_LEN) ce = S_LEN;    // 64-aligned

  // ---- staging decomposition: 512 uint4 per array, 2 per thread each ----
  const int f0 = tid, f1 = tid + 256;
  const int r0s = f0 >> 3, c0s = (f0 & 7) * 8;  // row, half-offset
  const int r1s = f1 >> 3, c1s = (f1 & 7) * 8;

  uint4 kreg0, kreg1, vreg0, vreg1;
  auto stage_load = [&](int c) {
    kreg0 = *(const uint4*)(Kp + (size_t)(c + r0s) * DH + c0s);
    kreg1 = *(const uint4*)(Kp + (size_t)(c + r1s) * DH + c1s);
    vreg0 = *(const uint4*)(Vp + (size_t)r0s * S_LEN + c + c0s);
    vreg1 = *(const uint4*)(Vp + (size_t)r1s * S_LEN + c + c1s);
  };
  auto stage_write = [&](int buf) {
    *(uint4*)&KsL[buf][r0s * 72 + c0s] = kreg0;
    *(uint4*)&KsL[buf][r1s * 72 + c1s] = kreg1;
    *(uint4*)&VsL[buf][r0s * 72 + c0s] = vreg0;
    *(uint4*)&VsL[buf][r1s * 72 + c1s] = vreg1;
  };

  auto compute = [&](int c, int buf) {
    // K frags + QK (S^T = K Q^T)
    floatx4 s[4];
    #pragma unroll
    for (int jt = 0; jt < 4; ++jt) {
      half8 k0 = *(const half8*)&KsL[buf][(jt * 16 + ln) * 72 + quad * 8];
      half8 k1 = *(const half8*)&KsL[buf][(jt * 16 + ln) * 72 + 32 + quad * 8];
      floatx4 z = (floatx4){0.f, 0.f, 0.f, 0.f};
      z = __builtin_amdgcn_mfma_f32_16x16x32_f16(k0, bq0, z, 0, 0, 0);
      s[jt] = __builtin_amdgcn_mfma_f32_16x16x32_f16(k1, bq1, z, 0, 0, 0);
    }
    // first half of V frags (dt 0..1) — consumed after softmax
    half4 v01[8];
    #pragma unroll
    for (int dt = 0; dt < 2; ++dt)
      #pragma unroll
      for (int jt = 0; jt < 4; ++jt)
        v01[dt * 4 + jt] =
            *(const half4*)&VsL[buf][(dt * 16 + ln) * 72 + jt * 16 + quad * 4];
    // mask + p = 2^(s*SC2 - 8); j=0 excluded (handled in init)
    const bool full_in = (c != 0) && (c >= qw - 241) && (c <= qw + 193);
    half4 Pt[4];
    if (full_in) {
      #pragma unroll
      for (int jt = 0; jt < 4; ++jt)
        #pragma unroll
        for (int r = 0; r < 4; ++r) {
          float pe = exp2f(fmaf(s[jt][r], SC2, -8.f));
          Pt[jt][r] = (fp16)pe;
          l_i += pe;
        }
    } else {
      const int q = qw + ln;
      #pragma unroll
      for (int jt = 0; jt < 4; ++jt) {
        #pragma unroll
        for (int r = 0; r < 4; ++r) {
          int j = c + jt * 16 + quad * 4 + r;
          int dq = q - j;
          bool ok = (dq <= WIN && dq >= -WIN) && (j != 0);
          float pe = ok ? exp2f(fmaf(s[jt][r], SC2, -8.f)) : 0.f;
          Pt[jt][r] = (fp16)pe;
          l_i += pe;
        }
      }
    }
    // second half of V frags (dt 2..3), then PV
    half4 v23[8];
    #pragma unroll
    for (int dt = 0; dt < 2; ++dt)
      #pragma unroll
      for (int jt = 0; jt < 4; ++jt)
        v23[dt * 4 + jt] =
            *(const half4*)&VsL[buf][((dt + 2) * 16 + ln) * 72 + jt * 16 + quad * 4];
    #pragma unroll
    for (int jt = 0; jt < 4; ++jt) {
      acc[0] = __builtin_amdgcn_mfma_f32_16x16x16f16(v01[jt], Pt[jt], acc[0], 0, 0, 0);
      acc[1] = __builtin_amdgcn_mfma_f32_16x16x16f16(v01[4 + jt], Pt[jt], acc[1], 0, 0, 0);
    }
    #pragma unroll
    for (int jt = 0; jt < 4; ++jt) {
      acc[2] = __builtin_amdgcn_mfma_f32_16x16x16f16(v23[jt], Pt[jt], acc[2], 0, 0, 0);
      acc[3] = __builtin_amdgcn_mfma_f32_16x16x16f16(v23[4 + jt], Pt[jt], acc[3], 0, 0, 0);
    }
  };

  // ---- pipelined loop: load c+1 -> compute c -> write c+1 -> barrier ----
  stage_load(cs);
  stage_write(0);
  __syncthreads();
  int buf = 0;
  for (int c = cs; c < ce; c += 64) {
    const bool hasnext = (c + 64 < ce);
    if (hasnext) stage_load(c + 64);
    compute(c, buf);
    if (hasnext) stage_write(buf ^ 1);
    __syncthreads();
    buf ^= 1;
  }

  // ---- epilogue: reduce l over quads, normalize, store ----
  float lt = l_i;
  lt += __shfl_xor(lt, 16, 64);
  lt += __shfl_xor(lt, 32, 64);
  const float inv = 1.0f / lt;
  const int q = qw + ln;
  if (q != 0) {  // row 0 written by the tile==32 block
    #pragma unroll
    for (int dt = 0; dt < 4; ++dt) {
      ushort4 pk;
      pk.x = f2b(acc[dt][0] * inv);
      pk.y = f2b(acc[dt][1] * inv);
      pk.z = f2b(acc[dt][2] * inv);
      pk.w = f2b(acc[dt][3] * inv);
      *(ushort4*)&aout[(size_t)(b * S_LEN + q) * DM + h * DH + dt * 16 + quad * 4] = pk;
    }
  }
}

// ---------- launch ----------
extern "C" void kernel_launch(void* const* d_in, const int* in_sizes, int n_in,
                              void* d_out, int out_size, void* d_ws, size_t ws_size,
                              hipStream_t stream) {
  const float* x  = (const float*)d_in[0];
  const float* Wq = (const float*)d_in[1];
  const float* bq = (const float*)d_in[2];
  const float* Wk = (const float*)d_in[3];
  const float* bk = (const float*)d_in[4];
  const float* Wv = (const float*)d_in[5];
  const float* bv = (const float*)d_in[6];
  const float* Wo = (const float*)d_in[7];
  const float* bo = (const float*)d_in[8];
  float* out = (float*)d_out;

  const size_t SEG = (size_t)4096 * 1024;
  bf16* xb = (bf16*)d_ws;
  bf16* wT = xb + SEG;
  fp16* Qh = (fp16*)(wT + SEG);
  fp16* Kh = Qh + SEG;
  fp16* Vt = Kh + SEG;   // [bh][d][s]
  bf16* ao = (bf16*)(Vt + SEG);

  k_convert_x<<<dim3(4096), dim3(256), 0, stream>>>((const float4*)x, (ushort4*)xb);
  k_transpose_cvt<<<dim3(32, 32, 4), dim3(32, 8), 0, stream>>>(Wq, Wk, Wv, Wo, wT);
  k_gemm<0><<<dim3(24, 32), dim3(256), 0, stream>>>(xb, wT, bq, bk, bv, Qh, Kh, Vt, nullptr);
  k_attn<<<dim3(1056), dim3(256), 0, stream>>>(Qh, Kh, Vt, ao);
  k_gemm<1><<<dim3(8, 32), dim3(256), 0, stream>>>(ao, wT + (size_t)3 * 1024 * 1024, bo,
                                                   nullptr, nullptr, nullptr, nullptr, nullptr, out);
}

// Round 8
// 195.787 us; speedup vs baseline: 1.9051x; 1.0617x over previous
//
#include <hip/hip_runtime.h>
#include <hip/hip_bf16.h>

typedef __attribute__((ext_vector_type(8))) short short8;
typedef __attribute__((ext_vector_type(4))) float floatx4;
typedef __attribute__((ext_vector_type(8))) _Float16 half8;
typedef __attribute__((ext_vector_type(4))) _Float16 half4;

using bf16 = __hip_bfloat16;
using fp16 = _Float16;

#define S_LEN 2048
#define DM 1024
#define NH 16
#define DH 64
#define WIN 256

// ---------- helpers ----------
__device__ __forceinline__ unsigned short f2b(float f) {
  __hip_bfloat16 h = __float2bfloat16(f);
  return *reinterpret_cast<unsigned short*>(&h);
}
__device__ __forceinline__ unsigned short f2h(float f) {
  fp16 h = (fp16)f;
  return *reinterpret_cast<unsigned short*>(&h);
}
__device__ __forceinline__ void lds_load16(void* lds, const void* gptr) {
  __builtin_amdgcn_global_load_lds(
      (const __attribute__((address_space(1))) unsigned int*)gptr,
      (__attribute__((address_space(3))) unsigned int*)lds, 16, 0, 0);
}

// ---------- K1: fused prep. z<4: W[k][n] fp32 -> Wt[n][k] bf16; z==4: x fp32->bf16 ----------
__global__ __launch_bounds__(256) void k_prep(const float* __restrict__ x,
                                              const float* __restrict__ W0,
                                              const float* __restrict__ W1,
                                              const float* __restrict__ W2,
                                              const float* __restrict__ W3,
                                              bf16* __restrict__ wT,
                                              ushort4* __restrict__ xb) {
  const int tx = threadIdx.x, ty = threadIdx.y;  // block (32,8)
  if (blockIdx.z == 4) {
    // convert x: 2*2048*1024 floats = 1048576 float4, 1024 blocks x 256 thr x 4
    const int tid = ty * 32 + tx;
    const int blk = blockIdx.y * 32 + blockIdx.x;
    const float4* in4 = (const float4*)x;
    #pragma unroll
    for (int k = 0; k < 4; ++k) {
      int i = k * 262144 + blk * 256 + tid;
      float4 v = in4[i];
      ushort4 o;
      o.x = f2b(v.x); o.y = f2b(v.y); o.z = f2b(v.z); o.w = f2b(v.w);
      xb[i] = o;
    }
    return;
  }
  __shared__ float t[32][33];
  const float* W = (blockIdx.z == 0) ? W0 : (blockIdx.z == 1) ? W1 : (blockIdx.z == 2) ? W2 : W3;
  bf16* O = wT + (size_t)blockIdx.z * 1024 * 1024;
  int x0 = blockIdx.x * 32, y0 = blockIdx.y * 32;
  #pragma unroll
  for (int i = 0; i < 32; i += 8) t[ty + i][tx] = W[(size_t)(y0 + ty + i) * 1024 + x0 + tx];
  __syncthreads();
  #pragma unroll
  for (int i = 0; i < 32; i += 8)
    O[(size_t)(x0 + ty + i) * 1024 + y0 + tx] = __float2bfloat16(t[tx][ty + i]);
}

// ---------- K2/K4: bf16 MFMA GEMM, C = A[M][1024] * Bt[N][1024]^T, BK=64 ----------
// 1D grid, XCD swizzle: xcd=i&7, m_tile=xcd*4+(r&3) -> A-tiles L2-resident.
// MODE 0: N=3072 (Wq|Wk|Wv) -> Qh/Kh [bh][s][64] fp16; V transposed: Vt [bh][d][s] fp16
// MODE 1: N=1024 (Wo) -> fp32 [m][1024]
template <int MODE>
__global__ __launch_bounds__(256) void k_gemm(const bf16* __restrict__ A,
                                              const bf16* __restrict__ Bt,
                                              const float* __restrict__ bias_q,
                                              const float* __restrict__ bias_k,
                                              const float* __restrict__ bias_v,
                                              fp16* __restrict__ Qh, fp16* __restrict__ Kh,
                                              fp16* __restrict__ Vt, float* __restrict__ outF) {
  __shared__ __align__(16) bf16 As[2][128 * 32];  // [khalf][row*32+col]
  __shared__ __align__(16) bf16 Bs[2][128 * 32];
  const int tid = threadIdx.x;
  const int wave = tid >> 6, lane = tid & 63;
  const int gi = blockIdx.x;
  const int xcd = gi & 7, grr = gi >> 3;
  const int m0 = (xcd * 4 + (grr & 3)) * 128;
  const int n0 = (grr >> 2) * 128;
  const int r0 = tid >> 2;
  const int cb = (tid & 3) * 16;
  const char* Ag = (const char*)A + (size_t)(m0 + r0) * 2048 + cb;
  const char* Bg = (const char*)Bt + (size_t)(n0 + r0) * 2048 + cb;
  char* As0W = (char*)&As[0][0] + wave * 1024;
  char* As1W = (char*)&As[1][0] + wave * 1024;
  char* Bs0W = (char*)&Bs[0][0] + wave * 1024;
  char* Bs1W = (char*)&Bs[1][0] + wave * 1024;
  const int wm = (wave & 1) * 64, wn = (wave >> 1) * 64;
  const int ln = lane & 15, quad = lane >> 4;

  floatx4 acc[4][4];
  #pragma unroll
  for (int i = 0; i < 4; i++)
    #pragma unroll
    for (int j = 0; j < 4; j++) acc[i][j] = (floatx4){0.f, 0.f, 0.f, 0.f};

  for (int k0 = 0; k0 < 1024; k0 += 64) {
    __syncthreads();
    lds_load16(As0W,        Ag + k0 * 2);
    lds_load16(As0W + 4096, Ag + 64 * 2048 + k0 * 2);
    lds_load16(As1W,        Ag + k0 * 2 + 64);
    lds_load16(As1W + 4096, Ag + 64 * 2048 + k0 * 2 + 64);
    lds_load16(Bs0W,        Bg + k0 * 2);
    lds_load16(Bs0W + 4096, Bg + 64 * 2048 + k0 * 2);
    lds_load16(Bs1W,        Bg + k0 * 2 + 64);
    lds_load16(Bs1W + 4096, Bg + 64 * 2048 + k0 * 2 + 64);
    __syncthreads();
    short8 af0[4], af1[4], bf0[4], bf1[4];
    #pragma unroll
    for (int mi = 0; mi < 4; mi++) {
      af0[mi] = *(const short8*)&As[0][(wm + mi * 16 + ln) * 32 + quad * 8];
      af1[mi] = *(const short8*)&As[1][(wm + mi * 16 + ln) * 32 + quad * 8];
    }
    #pragma unroll
    for (int ni = 0; ni < 4; ni++) {
      bf0[ni] = *(const short8*)&Bs[0][(wn + ni * 16 + ln) * 32 + quad * 8];
      bf1[ni] = *(const short8*)&Bs[1][(wn + ni * 16 + ln) * 32 + quad * 8];
    }
    #pragma unroll
    for (int mi = 0; mi < 4; mi++)
      #pragma unroll
      for (int ni = 0; ni < 4; ni++) {
        acc[mi][ni] = __builtin_amdgcn_mfma_f32_16x16x32_bf16(af0[mi], bf0[ni], acc[mi][ni], 0, 0, 0);
        acc[mi][ni] = __builtin_amdgcn_mfma_f32_16x16x32_bf16(af1[mi], bf1[ni], acc[mi][ni], 0, 0, 0);
      }
  }

  if constexpr (MODE == 0) {
    #pragma unroll
    for (int ni = 0; ni < 4; ni++) {
      int n = n0 + wn + ni * 16 + ln;  // 0..3071; g uniform across the wave
      int g = n >> 10, nn = n & 1023;
      int h = nn >> 6, dd = nn & 63;
      if (g == 2) {  // V -> Vt[bh][d][s] fp16, 4 consecutive s per 8B store
        float bias = bias_v[nn];
        #pragma unroll
        for (int mi = 0; mi < 4; mi++) {
          int m = m0 + wm + mi * 16 + quad * 4;
          int b = m >> 11, s = m & 2047;
          ushort4 pk;
          pk.x = f2h(acc[mi][ni][0] + bias);
          pk.y = f2h(acc[mi][ni][1] + bias);
          pk.z = f2h(acc[mi][ni][2] + bias);
          pk.w = f2h(acc[mi][ni][3] + bias);
          *(ushort4*)&Vt[((size_t)(b * NH + h) * DH + dd) * S_LEN + s] = pk;
        }
      } else {
        const float* bp = (g == 0) ? bias_q : bias_k;
        fp16* og = (g == 0) ? Qh : Kh;
        float bias = bp[nn];
        #pragma unroll
        for (int mi = 0; mi < 4; mi++) {
          #pragma unroll
          for (int r = 0; r < 4; r++) {
            int m = m0 + wm + mi * 16 + quad * 4 + r;
            int b = m >> 11, s = m & 2047;
            og[(size_t)((b * NH + h) * S_LEN + s) * DH + dd] = (fp16)(acc[mi][ni][r] + bias);
          }
        }
      }
    }
  } else {
    #pragma unroll
    for (int ni = 0; ni < 4; ni++) {
      int n = n0 + wn + ni * 16 + ln;
      float bias = bias_q[n];
      #pragma unroll
      for (int mi = 0; mi < 4; mi++)
        #pragma unroll
        for (int r = 0; r < 4; r++) {
          int m = m0 + wm + mi * 16 + quad * 4 + r;
          outF[(size_t)m * 1024 + n] = acc[mi][ni][r] + bias;
        }
    }
  }
}

// ---------- K3: LDS-staged double-buffered MFMA flash attention ----------
// (unchanged from round 7 — isolates the GEMM changes)
__global__ __launch_bounds__(256, 4) void k_attn(const fp16* __restrict__ Qh,
                                                 const fp16* __restrict__ Kh,
                                                 const fp16* __restrict__ Vt,
                                                 bf16* __restrict__ aout) {
  __shared__ __align__(16) fp16 KsL[2][64 * 72];
  __shared__ __align__(16) fp16 VsL[2][64 * 72];

  const int i = blockIdx.x;
  const int xcd = i & 7, rr = i >> 3;
  const int bh = xcd * 4 + (rr & 3);
  const int tile = rr >> 2;  // 0..32
  const int b = bh >> 4, h = bh & 15;
  const size_t base = (size_t)bh * S_LEN * DH;
  const fp16* Qp = Qh + base;
  const fp16* Kp = Kh + base;
  const fp16* Vp = Vt + base;  // [d][s]
  const float SC2 = 0.18033688011112042f;  // 0.125 * log2(e)
  const int tid = threadIdx.x;

  if (tile == 32) {
    // ===== global query row q=0: softmax over ALL 2048 keys, 4 waves =====
    float* sP = (float*)&KsL[0][0];
    float* oR = (float*)&VsL[0][0];
    float* red = (float*)&VsL[1][0];
    const int wv = tid >> 6, lane = tid & 63;
    const int g = lane >> 3, e8 = lane & 7;
    const half8 q0t = *(const half8*)(Qp + e8 * 8);
    float lsum = 0.f;
    for (int it = 0; it < 64; ++it) {
      int grp = wv * 64 + it;  // key j = grp*8 + g
      const half8 kv = *(const half8*)(Kp + (size_t)(grp * 8 + g) * DH + e8 * 8);
      float p = 0.f;
      #pragma unroll
      for (int e = 0; e < 8; ++e) p += (float)q0t[e] * (float)kv[e];
      p += __shfl_xor(p, 1, 64);
      p += __shfl_xor(p, 2, 64);
      p += __shfl_xor(p, 4, 64);
      p = exp2f(fmaf(p, SC2, -8.f));
      if (e8 == 0) sP[grp * 8 + g] = p;
      lsum += p;  // 8x duplicated; divide later
    }
    #pragma unroll
    for (int off = 1; off < 64; off <<= 1) lsum += __shfl_xor(lsum, off, 64);
    if (lane == 0) red[wv] = lsum;
    __syncthreads();
    const float ltot = (red[0] + red[1] + red[2] + red[3]) * 0.125f;
    const int d = tid & 63, qu = tid >> 6;
    float o = 0.f;
    for (int j0 = qu * 512; j0 < qu * 512 + 512; j0 += 8) {
      half8 vv = *(const half8*)(Vp + (size_t)d * S_LEN + j0);
      #pragma unroll
      for (int e = 0; e < 8; ++e) o += sP[j0 + e] * (float)vv[e];
    }
    oR[tid] = o;
    __syncthreads();
    if (tid < 64) {
      float oo = oR[tid] + oR[tid + 64] + oR[tid + 128] + oR[tid + 192];
      aout[(size_t)(b * S_LEN) * DM + h * DH + tid] = __float2bfloat16(oo / ltot);
    }
    return;
  }

  // ===== window tiles: 4 waves x 16 queries, block covers 64 q =====
  const int w = tid >> 6, lane = tid & 63;
  const int ln = lane & 15, quad = lane >> 4;
  const int qb = tile * 64;
  const int qw = qb + w * 16;

  const half8 bq0 = *(const half8*)(Qp + (size_t)(qw + ln) * DH + quad * 8);
  const half8 bq1 = *(const half8*)(Qp + (size_t)(qw + ln) * DH + 32 + quad * 8);

  floatx4 acc[4];  // O^T tiles: d = dt*16+quad*4+r, col q = ln
  float l_i;

  // ---- init: fold global key j=0 (p0 broadcast after shfls) ----
  {
    const half8 k0a = *(const half8*)(Kp + quad * 8);
    const half8 k0b = *(const half8*)(Kp + 32 + quad * 8);
    float s0 = 0.f;
    #pragma unroll
    for (int e = 0; e < 8; ++e)
      s0 += (float)bq0[e] * (float)k0a[e] + (float)bq1[e] * (float)k0b[e];
    s0 += __shfl_xor(s0, 16, 64);
    s0 += __shfl_xor(s0, 32, 64);
    float p0 = exp2f(fmaf(s0, SC2, -8.f));
    l_i = (quad == 0) ? p0 : 0.f;  // count j=0 once per q row
    #pragma unroll
    for (int dt = 0; dt < 4; ++dt)
      #pragma unroll
      for (int r = 0; r < 4; ++r)
        acc[dt][r] = p0 * (float)Vp[(size_t)(dt * 16 + quad * 4 + r) * S_LEN];
  }

  // ---- block-uniform chunk range ----
  int cs = qb - WIN; if (cs < 0) cs = 0;
  int ce = qb + 64 + WIN; if (ce > S_LEN) ce = S_LEN;

  // ---- staging decomposition: 512 uint4 per array, 2 per thread each ----
  const int f0 = tid, f1 = tid + 256;
  const int r0s = f0 >> 3, c0s = (f0 & 7) * 8;
  const int r1s = f1 >> 3, c1s = (f1 & 7) * 8;

  uint4 kreg0, kreg1, vreg0, vreg1;
  auto stage_load = [&](int c) {
    kreg0 = *(const uint4*)(Kp + (size_t)(c + r0s) * DH + c0s);
    kreg1 = *(const uint4*)(Kp + (size_t)(c + r1s) * DH + c1s);
    vreg0 = *(const uint4*)(Vp + (size_t)r0s * S_LEN + c + c0s);
    vreg1 = *(const uint4*)(Vp + (size_t)r1s * S_LEN + c + c1s);
  };
  auto stage_write = [&](int buf) {
    *(uint4*)&KsL[buf][r0s * 72 + c0s] = kreg0;
    *(uint4*)&KsL[buf][r1s * 72 + c1s] = kreg1;
    *(uint4*)&VsL[buf][r0s * 72 + c0s] = vreg0;
    *(uint4*)&VsL[buf][r1s * 72 + c1s] = vreg1;
  };

  auto compute = [&](int c, int buf) {
    floatx4 s[4];
    #pragma unroll
    for (int jt = 0; jt < 4; ++jt) {
      half8 k0 = *(const half8*)&KsL[buf][(jt * 16 + ln) * 72 + quad * 8];
      half8 k1 = *(const half8*)&KsL[buf][(jt * 16 + ln) * 72 + 32 + quad * 8];
      floatx4 z = (floatx4){0.f, 0.f, 0.f, 0.f};
      z = __builtin_amdgcn_mfma_f32_16x16x32_f16(k0, bq0, z, 0, 0, 0);
      s[jt] = __builtin_amdgcn_mfma_f32_16x16x32_f16(k1, bq1, z, 0, 0, 0);
    }
    half4 v01[8];
    #pragma unroll
    for (int dt = 0; dt < 2; ++dt)
      #pragma unroll
      for (int jt = 0; jt < 4; ++jt)
        v01[dt * 4 + jt] =
            *(const half4*)&VsL[buf][(dt * 16 + ln) * 72 + jt * 16 + quad * 4];
    const bool full_in = (c != 0) && (c >= qw - 241) && (c <= qw + 193);
    half4 Pt[4];
    if (full_in) {
      #pragma unroll
      for (int jt = 0; jt < 4; ++jt)
        #pragma unroll
        for (int r = 0; r < 4; ++r) {
          float pe = exp2f(fmaf(s[jt][r], SC2, -8.f));
          Pt[jt][r] = (fp16)pe;
          l_i += pe;
        }
    } else {
      const int q = qw + ln;
      #pragma unroll
      for (int jt = 0; jt < 4; ++jt) {
        #pragma unroll
        for (int r = 0; r < 4; ++r) {
          int j = c + jt * 16 + quad * 4 + r;
          int dq = q - j;
          bool ok = (dq <= WIN && dq >= -WIN) && (j != 0);
          float pe = ok ? exp2f(fmaf(s[jt][r], SC2, -8.f)) : 0.f;
          Pt[jt][r] = (fp16)pe;
          l_i += pe;
        }
      }
    }
    half4 v23[8];
    #pragma unroll
    for (int dt = 0; dt < 2; ++dt)
      #pragma unroll
      for (int jt = 0; jt < 4; ++jt)
        v23[dt * 4 + jt] =
            *(const half4*)&VsL[buf][((dt + 2) * 16 + ln) * 72 + jt * 16 + quad * 4];
    #pragma unroll
    for (int jt = 0; jt < 4; ++jt) {
      acc[0] = __builtin_amdgcn_mfma_f32_16x16x16f16(v01[jt], Pt[jt], acc[0], 0, 0, 0);
      acc[1] = __builtin_amdgcn_mfma_f32_16x16x16f16(v01[4 + jt], Pt[jt], acc[1], 0, 0, 0);
    }
    #pragma unroll
    for (int jt = 0; jt < 4; ++jt) {
      acc[2] = __builtin_amdgcn_mfma_f32_16x16x16f16(v23[jt], Pt[jt], acc[2], 0, 0, 0);
      acc[3] = __builtin_amdgcn_mfma_f32_16x16x16f16(v23[4 + jt], Pt[jt], acc[3], 0, 0, 0);
    }
  };

  stage_load(cs);
  stage_write(0);
  __syncthreads();
  int buf = 0;
  for (int c = cs; c < ce; c += 64) {
    const bool hasnext = (c + 64 < ce);
    if (hasnext) stage_load(c + 64);
    compute(c, buf);
    if (hasnext) stage_write(buf ^ 1);
    __syncthreads();
    buf ^= 1;
  }

  float lt = l_i;
  lt += __shfl_xor(lt, 16, 64);
  lt += __shfl_xor(lt, 32, 64);
  const float inv = 1.0f / lt;
  const int q = qw + ln;
  if (q != 0) {
    #pragma unroll
    for (int dt = 0; dt < 4; ++dt) {
      ushort4 pk;
      pk.x = f2b(acc[dt][0] * inv);
      pk.y = f2b(acc[dt][1] * inv);
      pk.z = f2b(acc[dt][2] * inv);
      pk.w = f2b(acc[dt][3] * inv);
      *(ushort4*)&aout[(size_t)(b * S_LEN + q) * DM + h * DH + dt * 16 + quad * 4] = pk;
    }
  }
}

// ---------- launch ----------
extern "C" void kernel_launch(void* const* d_in, const int* in_sizes, int n_in,
                              void* d_out, int out_size, void* d_ws, size_t ws_size,
                              hipStream_t stream) {
  const float* x  = (const float*)d_in[0];
  const float* Wq = (const float*)d_in[1];
  const float* bq = (const float*)d_in[2];
  const float* Wk = (const float*)d_in[3];
  const float* bk = (const float*)d_in[4];
  const float* Wv = (const float*)d_in[5];
  const float* bv = (const float*)d_in[6];
  const float* Wo = (const float*)d_in[7];
  const float* bo = (const float*)d_in[8];
  float* out = (float*)d_out;

  const size_t SEG = (size_t)4096 * 1024;
  bf16* xb = (bf16*)d_ws;
  bf16* wT = xb + SEG;
  fp16* Qh = (fp16*)(wT + SEG);
  fp16* Kh = Qh + SEG;
  fp16* Vt = Kh + SEG;   // [bh][d][s]
  bf16* ao = (bf16*)(Vt + SEG);

  k_prep<<<dim3(32, 32, 5), dim3(32, 8), 0, stream>>>(x, Wq, Wk, Wv, Wo, wT, (ushort4*)xb);
  k_gemm<0><<<dim3(768), dim3(256), 0, stream>>>(xb, wT, bq, bk, bv, Qh, Kh, Vt, nullptr);
  k_attn<<<dim3(1056), dim3(256), 0, stream>>>(Qh, Kh, Vt, ao);
  k_gemm<1><<<dim3(256), dim3(256), 0, stream>>>(ao, wT + (size_t)3 * 1024 * 1024, bo,
                                                 nullptr, nullptr, nullptr, nullptr, nullptr, out);
}